// Round 1
// baseline (1904.362 us; speedup 1.0000x reference)
//
#include <hip/hip_runtime.h>
#include <stdint.h>

typedef __attribute__((ext_vector_type(8))) short v8s;
typedef __attribute__((ext_vector_type(4))) float v4f;

#define MFMA(a, b, c) __builtin_amdgcn_mfma_f32_16x16x32_bf16((a), (b), (c), 0, 0, 0)

__device__ __forceinline__ unsigned short f2bf(float f) {
    unsigned int u = __float_as_uint(f);
    u += 0x7fffu + ((u >> 16) & 1u);           // RNE, inputs are finite
    return (unsigned short)(u >> 16);
}
__device__ __forceinline__ float bf2f(unsigned short h) {
    return __uint_as_float(((unsigned int)h) << 16);
}

#define NB 4
#define SEQ 4096
#define ED 1024

// ---- workspace byte offsets (total 232 MB) ----
#define XHI_OFF   (0ll)
#define XLO_OFF   (33554432ll)
#define WTQH_OFF  (67108864ll)
#define WTQL_OFF  (69206016ll)
#define WTKH_OFF  (71303168ll)
#define WTKL_OFF  (73400320ll)
#define QHI_OFF   (75497472ll)
#define QLO_OFF   (109051904ll)
#define KHI_OFF   (142606336ll)
#define KLO_OFF   (176160768ll)
#define XT_OFF    (209715200ll)
#define WS_NEED   (243269632ll)

// ============ prep_x: split X -> bf16 hi/lo, and transpose -> XT[b][d][s] ============
__global__ __launch_bounds__(256) void prep_x(const float* __restrict__ x,
                                              unsigned short* __restrict__ xhi,
                                              unsigned short* __restrict__ xlo,
                                              unsigned short* __restrict__ xt) {
    __shared__ float tile[64][65];
    int b = blockIdx.z, s0 = blockIdx.x * 64, d0 = blockIdx.y * 64;
    int t = threadIdx.x;
#pragma unroll
    for (int i = 0; i < 16; ++i) {
        int idx = t + i * 256;
        int r = idx >> 6, c = idx & 63;
        long gi = (long)(b * SEQ + s0 + r) * ED + d0 + c;
        float v = x[gi];
        tile[r][c] = v;
        unsigned short hi = f2bf(v);
        xhi[gi] = hi;
        xlo[gi] = f2bf(v - bf2f(hi));
    }
    __syncthreads();
#pragma unroll
    for (int i = 0; i < 16; ++i) {
        int idx = t + i * 256;
        int r = idx >> 6, c = idx & 63;   // r: local d, c: local s
        xt[(long)(b * ED + d0 + r) * SEQ + s0 + c] = f2bf(tile[c][r]);
    }
}

// ============ prep_w: W[e][f] -> WT[f][e] split hi/lo ============
__global__ __launch_bounds__(256) void prep_w(const float* __restrict__ wq,
                                              const float* __restrict__ wk,
                                              unsigned short* __restrict__ wtqh,
                                              unsigned short* __restrict__ wtql,
                                              unsigned short* __restrict__ wtkh,
                                              unsigned short* __restrict__ wtkl) {
    __shared__ float tile[64][65];
    const float* w = blockIdx.z ? wk : wq;
    unsigned short* oh = blockIdx.z ? wtkh : wtqh;
    unsigned short* ol = blockIdx.z ? wtkl : wtql;
    int e0 = blockIdx.x * 64, f0 = blockIdx.y * 64;
    int t = threadIdx.x;
#pragma unroll
    for (int i = 0; i < 16; ++i) {
        int idx = t + i * 256;
        int r = idx >> 6, c = idx & 63;
        tile[r][c] = w[(long)(e0 + r) * ED + f0 + c];
    }
    __syncthreads();
#pragma unroll
    for (int i = 0; i < 16; ++i) {
        int idx = t + i * 256;
        int r = idx >> 6, c = idx & 63;   // out row f0+r, col e0+c
        float v = tile[c][r];
        unsigned short hi = f2bf(v);
        long o = (long)(f0 + r) * ED + e0 + c;
        oh[o] = hi;
        ol[o] = f2bf(v - bf2f(hi));
    }
}

// ============ proj: C[16384,1024] = A[16384,1024] x W, split-bf16 (3 mfma passes) ============
// A given as hi/lo, B^T (=W^T) given as hi/lo. 128x128 tile, BK=64, 4 waves.
__global__ __launch_bounds__(256, 2) void proj_gemm(const unsigned short* __restrict__ ah,
                                                    const unsigned short* __restrict__ al,
                                                    const unsigned short* __restrict__ bh,
                                                    const unsigned short* __restrict__ bl,
                                                    unsigned short* __restrict__ ch,
                                                    unsigned short* __restrict__ cl) {
    __shared__ __align__(16) unsigned char lds[65536]; // Ah|Al|Bh|Bl, 16KB each, [128][64]bf16 swizzled
    int m0 = blockIdx.x * 128, n0 = blockIdx.y * 128;
    int tid = threadIdx.x, lane = tid & 63, wave = tid >> 6;
    int mo = (wave & 1) * 64, no = (wave >> 1) * 64;
    v4f vzero = {0.f, 0.f, 0.f, 0.f};
    v4f acc[4][4];
#pragma unroll
    for (int i = 0; i < 4; ++i)
#pragma unroll
        for (int j = 0; j < 4; ++j) acc[i][j] = vzero;
    int cb0 = 16 * (lane >> 4);

    for (int ks = 0; ks < 16; ++ks) {
        __syncthreads();   // protect prior reads before overwrite
#pragma unroll
        for (int j = 0; j < 4; ++j) {
            int idx = (j * 256 + tid) * 16;
            int row = idx >> 7, cb = idx & 127;
            int sw = cb ^ ((row & 7) << 4);
            long abyte = ((long)(m0 + row) * ED + ks * 64) * 2 + cb;
            long bbyte = ((long)(n0 + row) * ED + ks * 64) * 2 + cb;
            v8s va = *(const v8s*)((const unsigned char*)ah + abyte);
            v8s vA = *(const v8s*)((const unsigned char*)al + abyte);
            v8s vb = *(const v8s*)((const unsigned char*)bh + bbyte);
            v8s vB = *(const v8s*)((const unsigned char*)bl + bbyte);
            *(v8s*)(lds +         row * 128 + sw) = va;
            *(v8s*)(lds + 16384 + row * 128 + sw) = vA;
            *(v8s*)(lds + 32768 + row * 128 + sw) = vb;
            *(v8s*)(lds + 49152 + row * 128 + sw) = vB;
        }
        __syncthreads();
#pragma unroll
        for (int kk = 0; kk < 2; ++kk) {
            v8s fah[4], fal[4], fbh[4], fbl[4];
#pragma unroll
            for (int i = 0; i < 4; ++i) {
                int ra = mo + i * 16 + (lane & 15);
                int ca = (kk * 64 + cb0) ^ ((ra & 7) << 4);
                fah[i] = *(const v8s*)(lds +         ra * 128 + ca);
                fal[i] = *(const v8s*)(lds + 16384 + ra * 128 + ca);
                int rb = no + i * 16 + (lane & 15);
                int cbb = (kk * 64 + cb0) ^ ((rb & 7) << 4);
                fbh[i] = *(const v8s*)(lds + 32768 + rb * 128 + cbb);
                fbl[i] = *(const v8s*)(lds + 49152 + rb * 128 + cbb);
            }
#pragma unroll
            for (int i = 0; i < 4; ++i)
#pragma unroll
                for (int j = 0; j < 4; ++j) {
                    acc[i][j] = MFMA(fah[i], fbh[j], acc[i][j]);
                    acc[i][j] = MFMA(fah[i], fbl[j], acc[i][j]);
                    acc[i][j] = MFMA(fal[i], fbh[j], acc[i][j]);
                }
        }
    }
    // epilogue: split fp32 acc -> hi/lo bf16
#pragma unroll
    for (int i = 0; i < 4; ++i)
#pragma unroll
        for (int j = 0; j < 4; ++j)
#pragma unroll
            for (int r = 0; r < 4; ++r) {
                int row = m0 + mo + i * 16 + (lane >> 4) * 4 + r;
                int col = n0 + no + j * 16 + (lane & 15);
                float v = acc[i][j][r];
                unsigned short hi = f2bf(v);
                long o = (long)row * ED + col;
                ch[o] = hi;
                cl[o] = f2bf(v - bf2f(hi));
            }
}

// ============ attn: flash attention, Bq=64 rows/block, Bk=128 keys/tile, 8 waves ============
#define QH_OFF 0
#define QL_OFF 8192
#define KH_OFF 16384
#define KL_OFF 32768
#define SS_OFF 49152              // S: [64][136] f32
#define PP_OFF 83968              // P: [64][128] bf16 (swizzled)
#define ML_OFF 100352
#define LL_OFF 100608
#define FS_OFF 100864
#define SMEM_SZ 101120

__global__ __launch_bounds__(512, 2) void attn(const unsigned short* __restrict__ qhi,
                                               const unsigned short* __restrict__ qlo,
                                               const unsigned short* __restrict__ khi,
                                               const unsigned short* __restrict__ klo,
                                               const unsigned short* __restrict__ xt,
                                               float* __restrict__ out) {
    __shared__ __align__(16) unsigned char sm[SMEM_SZ];
    int b = blockIdx.y, q0 = blockIdx.x * 64;
    int tid = threadIdx.x, lane = tid & 63, wave = tid >> 6;
    float* mL = (float*)(sm + ML_OFF);
    float* lL = (float*)(sm + LL_OFF);
    float* fsL = (float*)(sm + FS_OFF);
    if (tid < 64) { mL[tid] = -INFINITY; lL[tid] = 0.f; }
    v4f vzero = {0.f, 0.f, 0.f, 0.f};
    v4f acc[4][8];                 // wave owns O[64 q][128 d], d-slice = wave*128
#pragma unroll
    for (int i = 0; i < 4; ++i)
#pragma unroll
        for (int j = 0; j < 8; ++j) acc[i][j] = vzero;
    int cb0 = 16 * (lane >> 4);

    for (int kt = 0; kt < 32; ++kt) {
        v4f sacc[4];
#pragma unroll
        for (int i = 0; i < 4; ++i) sacc[i] = vzero;

        // ---- S = Q K^T (split bf16, 3 passes), K-dim in 16 steps of 64 ----
        for (int ks = 0; ks < 16; ++ks) {
            __syncthreads();   // protect prior tile reads (and init) before overwrite
            {   // stage Q hi/lo [64][64]
                int idx = tid * 16;
                int row = idx >> 7, cb = idx & 127;
                int sw = cb ^ ((row & 7) << 4);
                long qb = ((long)(b * SEQ + q0 + row) * ED + ks * 64) * 2 + cb;
                *(v8s*)(sm + QH_OFF + row * 128 + sw) = *(const v8s*)((const unsigned char*)qhi + qb);
                *(v8s*)(sm + QL_OFF + row * 128 + sw) = *(const v8s*)((const unsigned char*)qlo + qb);
            }
#pragma unroll
            for (int j = 0; j < 2; ++j) {   // stage K hi/lo [128][64]
                int idx = (j * 512 + tid) * 16;
                int row = idx >> 7, cb = idx & 127;
                int sw = cb ^ ((row & 7) << 4);
                long kb = ((long)(b * SEQ + kt * 128 + row) * ED + ks * 64) * 2 + cb;
                *(v8s*)(sm + KH_OFF + row * 128 + sw) = *(const v8s*)((const unsigned char*)khi + kb);
                *(v8s*)(sm + KL_OFF + row * 128 + sw) = *(const v8s*)((const unsigned char*)klo + kb);
            }
            __syncthreads();
#pragma unroll
            for (int kk = 0; kk < 2; ++kk) {
                int rk = wave * 16 + (lane & 15);
                int ck = (kk * 64 + cb0) ^ ((rk & 7) << 4);
                v8s fkh = *(const v8s*)(sm + KH_OFF + rk * 128 + ck);
                v8s fkl = *(const v8s*)(sm + KL_OFF + rk * 128 + ck);
#pragma unroll
                for (int mi = 0; mi < 4; ++mi) {
                    int rq = mi * 16 + (lane & 15);
                    int cq = (kk * 64 + cb0) ^ ((rq & 7) << 4);
                    v8s fqh = *(const v8s*)(sm + QH_OFF + rq * 128 + cq);
                    v8s fql = *(const v8s*)(sm + QL_OFF + rq * 128 + cq);
                    sacc[mi] = MFMA(fqh, fkh, sacc[mi]);
                    sacc[mi] = MFMA(fqh, fkl, sacc[mi]);
                    sacc[mi] = MFMA(fql, fkh, sacc[mi]);
                }
            }
        }
        // ---- write scaled S to LDS ----
#pragma unroll
        for (int mi = 0; mi < 4; ++mi)
#pragma unroll
            for (int r = 0; r < 4; ++r) {
                int row = mi * 16 + (lane >> 4) * 4 + r;
                int col = wave * 16 + (lane & 15);
                *(float*)(sm + SS_OFF + (row * 136 + col) * 4) = sacc[mi][r] * 0.03125f;
            }
        __syncthreads();
        // ---- online softmax: 8 threads per row ----
        {
            int row = tid >> 3, c0 = tid & 7;
            const float* srow = (const float*)(sm + SS_OFF) + row * 136;
            float sv[16];
            float pmax = -INFINITY;
#pragma unroll
            for (int j = 0; j < 16; ++j) { sv[j] = srow[c0 + j * 8]; pmax = fmaxf(pmax, sv[j]); }
#pragma unroll
            for (int o = 1; o < 8; o <<= 1) pmax = fmaxf(pmax, __shfl_xor(pmax, o));
            float mold = mL[row];
            float mnew = fmaxf(mold, pmax);
            float psum = 0.f;
#pragma unroll
            for (int j = 0; j < 16; ++j) {
                float p = __expf(sv[j] - mnew);
                psum += p;
                int c = c0 + j * 8;
                *(unsigned short*)(sm + PP_OFF + row * 256 + ((2 * c) ^ ((row & 7) << 4))) = f2bf(p);
            }
#pragma unroll
            for (int o = 1; o < 8; o <<= 1) psum += __shfl_xor(psum, o);
            if (c0 == 0) {
                float f = __expf(mold - mnew);
                fsL[row] = f;
                lL[row] = lL[row] * f + psum;
                mL[row] = mnew;
            }
        }
        __syncthreads();
        // ---- rescale O, then O += P @ X (plain bf16 PV, B-frags direct from XT) ----
#pragma unroll
        for (int mi = 0; mi < 4; ++mi)
#pragma unroll
            for (int r = 0; r < 4; ++r) {
                float f = fsL[mi * 16 + (lane >> 4) * 4 + r];
#pragma unroll
                for (int ni = 0; ni < 8; ++ni) acc[mi][ni][r] *= f;
            }
#pragma unroll
        for (int kk = 0; kk < 4; ++kk) {
            v8s pf[4];
#pragma unroll
            for (int mi = 0; mi < 4; ++mi) {
                int row = mi * 16 + (lane & 15);
                pf[mi] = *(const v8s*)(sm + PP_OFF + row * 256 + ((kk * 64 + cb0) ^ ((row & 7) << 4)));
            }
#pragma unroll
            for (int ni = 0; ni < 8; ++ni) {
                long d = wave * 128 + ni * 16 + (lane & 15);
                long key = (long)kt * 128 + kk * 32 + 8 * (lane >> 4);
                v8s xf = *(const v8s*)((const unsigned char*)xt + ((long)(b * ED + d) * SEQ + key) * 2);
#pragma unroll
                for (int mi = 0; mi < 4; ++mi)
                    acc[mi][ni] = MFMA(pf[mi], xf, acc[mi][ni]);
            }
        }
    }
    // ---- epilogue: out = acc / l ----
#pragma unroll
    for (int mi = 0; mi < 4; ++mi)
#pragma unroll
        for (int r = 0; r < 4; ++r) {
            float linv = 1.0f / lL[mi * 16 + (lane >> 4) * 4 + r];
#pragma unroll
            for (int ni = 0; ni < 8; ++ni) {
                long row = (long)b * SEQ + q0 + mi * 16 + (lane >> 4) * 4 + r;
                long col = wave * 128 + ni * 16 + (lane & 15);
                out[row * ED + col] = acc[mi][ni][r] * linv;
            }
        }
}

extern "C" void kernel_launch(void* const* d_in, const int* in_sizes, int n_in,
                              void* d_out, int out_size, void* d_ws, size_t ws_size,
                              hipStream_t stream) {
    const float* x  = (const float*)d_in[0];
    const float* wq = (const float*)d_in[1];
    const float* wk = (const float*)d_in[2];
    unsigned char* ws = (unsigned char*)d_ws;
    // NOTE: requires ws_size >= 232 MB (WS_NEED). If this round fails on ws, shrink by
    // dropping Xhi/Xlo (on-the-fly split) next round.
    unsigned short* xhi  = (unsigned short*)(ws + XHI_OFF);
    unsigned short* xlo  = (unsigned short*)(ws + XLO_OFF);
    unsigned short* wtqh = (unsigned short*)(ws + WTQH_OFF);
    unsigned short* wtql = (unsigned short*)(ws + WTQL_OFF);
    unsigned short* wtkh = (unsigned short*)(ws + WTKH_OFF);
    unsigned short* wtkl = (unsigned short*)(ws + WTKL_OFF);
    unsigned short* qhi  = (unsigned short*)(ws + QHI_OFF);
    unsigned short* qlo  = (unsigned short*)(ws + QLO_OFF);
    unsigned short* khi  = (unsigned short*)(ws + KHI_OFF);
    unsigned short* klo  = (unsigned short*)(ws + KLO_OFF);
    unsigned short* xt   = (unsigned short*)(ws + XT_OFF);

    prep_x<<<dim3(64, 16, 4), 256, 0, stream>>>(x, xhi, xlo, xt);
    prep_w<<<dim3(16, 16, 2), 256, 0, stream>>>(wq, wk, wtqh, wtql, wtkh, wtkl);
    proj_gemm<<<dim3(128, 8), 256, 0, stream>>>(xhi, xlo, wtqh, wtql, qhi, qlo);
    proj_gemm<<<dim3(128, 8), 256, 0, stream>>>(xhi, xlo, wtkh, wtkl, khi, klo);
    attn<<<dim3(64, 4), 512, 0, stream>>>(qhi, qlo, khi, klo, xt, (float*)d_out);
}

// Round 3
// 955.539 us; speedup vs baseline: 1.9930x; 1.9930x over previous
//
#include <hip/hip_runtime.h>
#include <stdint.h>

typedef __attribute__((ext_vector_type(8))) short v8s;
typedef __attribute__((ext_vector_type(4))) short v4s;
typedef __attribute__((ext_vector_type(4))) float v4f;

#define MFMA(a, b, c) __builtin_amdgcn_mfma_f32_16x16x32_bf16((a), (b), (c), 0, 0, 0)

__device__ __forceinline__ unsigned short f2bf(float f) {
    unsigned int u = __float_as_uint(f);
    u += 0x7fffu + ((u >> 16) & 1u);           // RNE, inputs are finite
    return (unsigned short)(u >> 16);
}
__device__ __forceinline__ float bf2f(unsigned short h) {
    return __uint_as_float(((unsigned int)h) << 16);
}

#define NB 4
#define SEQ 4096
#define ED 1024

// ---- workspace byte offsets (peak 232 MB — same as proven R1 requirement) ----
// xhi/xlo live only until the proj_gemm calls finish; then their 64 MB is
// reused as the per-batch fp32 S buffer (4096*4096*4 = 64 MB exactly).
#define XHI_OFF   (0ll)
#define XLO_OFF   (33554432ll)
#define SBUF_OFF  (0ll)           // aliases xhi/xlo after projections
#define WTQH_OFF  (67108864ll)
#define WTQL_OFF  (69206016ll)
#define WTKH_OFF  (71303168ll)
#define WTKL_OFF  (73400320ll)
#define QHI_OFF   (75497472ll)
#define QLO_OFF   (109051904ll)
#define KHI_OFF   (142606336ll)
#define KLO_OFF   (176160768ll)
#define XT_OFF    (209715200ll)
#define WS_NEED   (243269632ll)   // 232 MB

// ============ prep_x: split X -> bf16 hi/lo, and transpose -> XT[b][d][s] ============
__global__ __launch_bounds__(256) void prep_x(const float* __restrict__ x,
                                              unsigned short* __restrict__ xhi,
                                              unsigned short* __restrict__ xlo,
                                              unsigned short* __restrict__ xt) {
    __shared__ float tile[64][65];
    int b = blockIdx.z, s0 = blockIdx.x * 64, d0 = blockIdx.y * 64;
    int t = threadIdx.x;
#pragma unroll
    for (int i = 0; i < 16; ++i) {
        int idx = t + i * 256;
        int r = idx >> 6, c = idx & 63;
        long gi = (long)(b * SEQ + s0 + r) * ED + d0 + c;
        float v = x[gi];
        tile[r][c] = v;
        unsigned short hi = f2bf(v);
        xhi[gi] = hi;
        xlo[gi] = f2bf(v - bf2f(hi));
    }
    __syncthreads();
#pragma unroll
    for (int i = 0; i < 16; ++i) {
        int idx = t + i * 256;
        int r = idx >> 6, c = idx & 63;   // r: local d, c: local s
        xt[(long)(b * ED + d0 + r) * SEQ + s0 + c] = f2bf(tile[c][r]);
    }
}

// ============ prep_w: W[e][f] -> WT[f][e] split hi/lo ============
__global__ __launch_bounds__(256) void prep_w(const float* __restrict__ wq,
                                              const float* __restrict__ wk,
                                              unsigned short* __restrict__ wtqh,
                                              unsigned short* __restrict__ wtql,
                                              unsigned short* __restrict__ wtkh,
                                              unsigned short* __restrict__ wtkl) {
    __shared__ float tile[64][65];
    const float* w = blockIdx.z ? wk : wq;
    unsigned short* oh = blockIdx.z ? wtkh : wtqh;
    unsigned short* ol = blockIdx.z ? wtkl : wtql;
    int e0 = blockIdx.x * 64, f0 = blockIdx.y * 64;
    int t = threadIdx.x;
#pragma unroll
    for (int i = 0; i < 16; ++i) {
        int idx = t + i * 256;
        int r = idx >> 6, c = idx & 63;
        tile[r][c] = w[(long)(e0 + r) * ED + f0 + c];
    }
    __syncthreads();
#pragma unroll
    for (int i = 0; i < 16; ++i) {
        int idx = t + i * 256;
        int r = idx >> 6, c = idx & 63;   // out row f0+r, col e0+c
        float v = tile[c][r];
        unsigned short hi = f2bf(v);
        long o = (long)(f0 + r) * ED + e0 + c;
        oh[o] = hi;
        ol[o] = f2bf(v - bf2f(hi));
    }
}

// ============ proj: C[16384,1024] = A[16384,1024] x W, split-bf16 (3 mfma passes) ============
__global__ __launch_bounds__(256, 2) void proj_gemm(const unsigned short* __restrict__ ah,
                                                    const unsigned short* __restrict__ al,
                                                    const unsigned short* __restrict__ bh,
                                                    const unsigned short* __restrict__ bl,
                                                    unsigned short* __restrict__ ch,
                                                    unsigned short* __restrict__ cl) {
    __shared__ __align__(16) unsigned char lds[65536]; // Ah|Al|Bh|Bl, 16KB each, [128][64]bf16 swizzled
    int m0 = blockIdx.x * 128, n0 = blockIdx.y * 128;
    int tid = threadIdx.x, lane = tid & 63, wave = tid >> 6;
    int mo = (wave & 1) * 64, no = (wave >> 1) * 64;
    v4f vzero = {0.f, 0.f, 0.f, 0.f};
    v4f acc[4][4];
#pragma unroll
    for (int i = 0; i < 4; ++i)
#pragma unroll
        for (int j = 0; j < 4; ++j) acc[i][j] = vzero;
    int cb0 = 16 * (lane >> 4);

    for (int ks = 0; ks < 16; ++ks) {
        __syncthreads();
#pragma unroll
        for (int j = 0; j < 4; ++j) {
            int idx = (j * 256 + tid) * 16;
            int row = idx >> 7, cb = idx & 127;
            int sw = cb ^ ((row & 7) << 4);
            long abyte = ((long)(m0 + row) * ED + ks * 64) * 2 + cb;
            long bbyte = ((long)(n0 + row) * ED + ks * 64) * 2 + cb;
            v8s va = *(const v8s*)((const unsigned char*)ah + abyte);
            v8s vA = *(const v8s*)((const unsigned char*)al + abyte);
            v8s vb = *(const v8s*)((const unsigned char*)bh + bbyte);
            v8s vB = *(const v8s*)((const unsigned char*)bl + bbyte);
            *(v8s*)(lds +         row * 128 + sw) = va;
            *(v8s*)(lds + 16384 + row * 128 + sw) = vA;
            *(v8s*)(lds + 32768 + row * 128 + sw) = vb;
            *(v8s*)(lds + 49152 + row * 128 + sw) = vB;
        }
        __syncthreads();
#pragma unroll
        for (int kk = 0; kk < 2; ++kk) {
            v8s fah[4], fal[4], fbh[4], fbl[4];
#pragma unroll
            for (int i = 0; i < 4; ++i) {
                int ra = mo + i * 16 + (lane & 15);
                int ca = (kk * 64 + cb0) ^ ((ra & 7) << 4);
                fah[i] = *(const v8s*)(lds +         ra * 128 + ca);
                fal[i] = *(const v8s*)(lds + 16384 + ra * 128 + ca);
                int rb = no + i * 16 + (lane & 15);
                int cbb = (kk * 64 + cb0) ^ ((rb & 7) << 4);
                fbh[i] = *(const v8s*)(lds + 32768 + rb * 128 + cbb);
                fbl[i] = *(const v8s*)(lds + 49152 + rb * 128 + cbb);
            }
#pragma unroll
            for (int i = 0; i < 4; ++i)
#pragma unroll
                for (int j = 0; j < 4; ++j) {
                    acc[i][j] = MFMA(fah[i], fbh[j], acc[i][j]);
                    acc[i][j] = MFMA(fah[i], fbl[j], acc[i][j]);
                    acc[i][j] = MFMA(fal[i], fbh[j], acc[i][j]);
                }
        }
    }
#pragma unroll
    for (int i = 0; i < 4; ++i)
#pragma unroll
        for (int j = 0; j < 4; ++j)
#pragma unroll
            for (int r = 0; r < 4; ++r) {
                int row = m0 + mo + i * 16 + (lane >> 4) * 4 + r;
                int col = n0 + no + j * 16 + (lane & 15);
                float v = acc[i][j][r];
                unsigned short hi = f2bf(v);
                long o = (long)row * ED + col;
                ch[o] = hi;
                cl[o] = f2bf(v - bf2f(hi));
            }
}

// ============ gemm_s: S[q][k] = (Q K^T)/32 for one batch, fp32 into sbuf ============
__global__ __launch_bounds__(256, 2) void gemm_s(const unsigned short* __restrict__ qhi,
                                                 const unsigned short* __restrict__ qlo,
                                                 const unsigned short* __restrict__ khi,
                                                 const unsigned short* __restrict__ klo,
                                                 float* __restrict__ sbuf, int b) {
    __shared__ __align__(16) unsigned char lds[65536];
    int m0 = blockIdx.x * 128, n0 = blockIdx.y * 128;
    int tid = threadIdx.x, lane = tid & 63, wave = tid >> 6;
    int mo = (wave & 1) * 64, no = (wave >> 1) * 64;
    v4f vzero = {0.f, 0.f, 0.f, 0.f};
    v4f acc[4][4];
#pragma unroll
    for (int i = 0; i < 4; ++i)
#pragma unroll
        for (int j = 0; j < 4; ++j) acc[i][j] = vzero;
    int cb0 = 16 * (lane >> 4);

    for (int ks = 0; ks < 16; ++ks) {
        __syncthreads();
#pragma unroll
        for (int j = 0; j < 4; ++j) {
            int idx = (j * 256 + tid) * 16;
            int row = idx >> 7, cb = idx & 127;
            int sw = cb ^ ((row & 7) << 4);
            long abyte = ((long)(b * SEQ + m0 + row) * ED + ks * 64) * 2 + cb;
            long bbyte = ((long)(b * SEQ + n0 + row) * ED + ks * 64) * 2 + cb;
            v8s va = *(const v8s*)((const unsigned char*)qhi + abyte);
            v8s vA = *(const v8s*)((const unsigned char*)qlo + abyte);
            v8s vb = *(const v8s*)((const unsigned char*)khi + bbyte);
            v8s vB = *(const v8s*)((const unsigned char*)klo + bbyte);
            *(v8s*)(lds +         row * 128 + sw) = va;
            *(v8s*)(lds + 16384 + row * 128 + sw) = vA;
            *(v8s*)(lds + 32768 + row * 128 + sw) = vb;
            *(v8s*)(lds + 49152 + row * 128 + sw) = vB;
        }
        __syncthreads();
#pragma unroll
        for (int kk = 0; kk < 2; ++kk) {
            v8s fah[4], fal[4], fbh[4], fbl[4];
#pragma unroll
            for (int i = 0; i < 4; ++i) {
                int ra = mo + i * 16 + (lane & 15);
                int ca = (kk * 64 + cb0) ^ ((ra & 7) << 4);
                fah[i] = *(const v8s*)(lds +         ra * 128 + ca);
                fal[i] = *(const v8s*)(lds + 16384 + ra * 128 + ca);
                int rb = no + i * 16 + (lane & 15);
                int cbb = (kk * 64 + cb0) ^ ((rb & 7) << 4);
                fbh[i] = *(const v8s*)(lds + 32768 + rb * 128 + cbb);
                fbl[i] = *(const v8s*)(lds + 49152 + rb * 128 + cbb);
            }
#pragma unroll
            for (int i = 0; i < 4; ++i)
#pragma unroll
                for (int j = 0; j < 4; ++j) {
                    acc[i][j] = MFMA(fah[i], fbh[j], acc[i][j]);
                    acc[i][j] = MFMA(fah[i], fbl[j], acc[i][j]);
                    acc[i][j] = MFMA(fal[i], fbh[j], acc[i][j]);
                }
        }
    }
#pragma unroll
    for (int i = 0; i < 4; ++i)
#pragma unroll
        for (int j = 0; j < 4; ++j)
#pragma unroll
            for (int r = 0; r < 4; ++r) {
                int row = m0 + mo + i * 16 + (lane >> 4) * 4 + r;
                int col = n0 + no + j * 16 + (lane & 15);
                sbuf[(long)row * SEQ + col] = acc[i][j][r] * 0.03125f;
            }
}

// ============ softmax_rows: P = exp(S-m)/l, bf16, packed in-place (first 8KB of row) ============
__global__ __launch_bounds__(256) void softmax_rows(float* __restrict__ sbuf) {
    int row = blockIdx.x * 4 + (threadIdx.x >> 6);
    int lane = threadIdx.x & 63;
    float* base = sbuf + (long)row * SEQ;
    v4f v[16];
    float m = -INFINITY;
#pragma unroll
    for (int j = 0; j < 16; ++j) {
        v[j] = *(const v4f*)(base + j * 256 + lane * 4);
#pragma unroll
        for (int e = 0; e < 4; ++e) m = fmaxf(m, v[j][e]);
    }
#pragma unroll
    for (int o = 1; o < 64; o <<= 1) m = fmaxf(m, __shfl_xor(m, o));
    float s = 0.f;
#pragma unroll
    for (int j = 0; j < 16; ++j)
#pragma unroll
        for (int e = 0; e < 4; ++e) {
            float p = __expf(v[j][e] - m);
            s += p;
            v[j][e] = p;
        }
#pragma unroll
    for (int o = 1; o < 64; o <<= 1) s += __shfl_xor(s, o);
    float inv = 1.0f / s;
    unsigned short* ob = (unsigned short*)base;
#pragma unroll
    for (int j = 0; j < 16; ++j) {
        v4s pk;
#pragma unroll
        for (int e = 0; e < 4; ++e) pk[e] = (short)f2bf(v[j][e] * inv);
        *(v4s*)(ob + j * 256 + lane * 4) = pk;
    }
}

// ============ gemm_pv: O[q][d] = P X for one batch. A = P (16KB row slots), B^T = XT ============
__global__ __launch_bounds__(256, 4) void gemm_pv(const float* __restrict__ sbuf,
                                                  const unsigned short* __restrict__ xt,
                                                  float* __restrict__ out, int b) {
    __shared__ __align__(16) unsigned char lds[32768]; // A|B, 16KB each, [128][64]bf16 swizzled
    int m0 = blockIdx.x * 128, n0 = blockIdx.y * 128;
    int tid = threadIdx.x, lane = tid & 63, wave = tid >> 6;
    int mo = (wave & 1) * 64, no = (wave >> 1) * 64;
    const unsigned char* pbytes = (const unsigned char*)sbuf;
    v4f vzero = {0.f, 0.f, 0.f, 0.f};
    v4f acc[4][4];
#pragma unroll
    for (int i = 0; i < 4; ++i)
#pragma unroll
        for (int j = 0; j < 4; ++j) acc[i][j] = vzero;
    int cb0 = 16 * (lane >> 4);

    for (int ks = 0; ks < 64; ++ks) {
        __syncthreads();
#pragma unroll
        for (int j = 0; j < 4; ++j) {
            int idx = (j * 256 + tid) * 16;
            int row = idx >> 7, cb = idx & 127;
            int sw = cb ^ ((row & 7) << 4);
            long abyte = (long)(m0 + row) * 16384 + ks * 128 + cb;   // P row slot stride 16KB
            long bbyte = ((long)(b * ED + n0 + row) * SEQ + ks * 64) * 2 + cb;
            v8s va = *(const v8s*)(pbytes + abyte);
            v8s vb = *(const v8s*)((const unsigned char*)xt + bbyte);
            *(v8s*)(lds +         row * 128 + sw) = va;
            *(v8s*)(lds + 16384 + row * 128 + sw) = vb;
        }
        __syncthreads();
#pragma unroll
        for (int kk = 0; kk < 2; ++kk) {
            v8s fa[4], fb[4];
#pragma unroll
            for (int i = 0; i < 4; ++i) {
                int ra = mo + i * 16 + (lane & 15);
                int ca = (kk * 64 + cb0) ^ ((ra & 7) << 4);
                fa[i] = *(const v8s*)(lds +         ra * 128 + ca);
                int rb = no + i * 16 + (lane & 15);
                int cbb = (kk * 64 + cb0) ^ ((rb & 7) << 4);
                fb[i] = *(const v8s*)(lds + 16384 + rb * 128 + cbb);
            }
#pragma unroll
            for (int i = 0; i < 4; ++i)
#pragma unroll
                for (int j = 0; j < 4; ++j)
                    acc[i][j] = MFMA(fa[i], fb[j], acc[i][j]);
        }
    }
#pragma unroll
    for (int i = 0; i < 4; ++i)
#pragma unroll
        for (int j = 0; j < 4; ++j)
#pragma unroll
            for (int r = 0; r < 4; ++r) {
                int row = m0 + mo + i * 16 + (lane >> 4) * 4 + r;
                int col = n0 + no + j * 16 + (lane & 15);
                out[(long)(b * SEQ + row) * ED + col] = acc[i][j][r];
            }
}

extern "C" void kernel_launch(void* const* d_in, const int* in_sizes, int n_in,
                              void* d_out, int out_size, void* d_ws, size_t ws_size,
                              hipStream_t stream) {
    const float* x  = (const float*)d_in[0];
    const float* wq = (const float*)d_in[1];
    const float* wk = (const float*)d_in[2];
    unsigned char* ws = (unsigned char*)d_ws;
    unsigned short* xhi  = (unsigned short*)(ws + XHI_OFF);
    unsigned short* xlo  = (unsigned short*)(ws + XLO_OFF);
    unsigned short* wtqh = (unsigned short*)(ws + WTQH_OFF);
    unsigned short* wtql = (unsigned short*)(ws + WTQL_OFF);
    unsigned short* wtkh = (unsigned short*)(ws + WTKH_OFF);
    unsigned short* wtkl = (unsigned short*)(ws + WTKL_OFF);
    unsigned short* qhi  = (unsigned short*)(ws + QHI_OFF);
    unsigned short* qlo  = (unsigned short*)(ws + QLO_OFF);
    unsigned short* khi  = (unsigned short*)(ws + KHI_OFF);
    unsigned short* klo  = (unsigned short*)(ws + KLO_OFF);
    unsigned short* xt   = (unsigned short*)(ws + XT_OFF);
    float*          sbuf = (float*)(ws + SBUF_OFF);   // aliases xhi/xlo, used only after proj

    prep_x<<<dim3(64, 16, 4), 256, 0, stream>>>(x, xhi, xlo, xt);
    prep_w<<<dim3(16, 16, 2), 256, 0, stream>>>(wq, wk, wtqh, wtql, wtkh, wtkl);
    proj_gemm<<<dim3(128, 8), 256, 0, stream>>>(xhi, xlo, wtqh, wtql, qhi, qlo);
    proj_gemm<<<dim3(128, 8), 256, 0, stream>>>(xhi, xlo, wtkh, wtkl, khi, klo);
    for (int b = 0; b < NB; ++b) {
        gemm_s<<<dim3(32, 32), 256, 0, stream>>>(qhi, qlo, khi, klo, sbuf, b);
        softmax_rows<<<1024, 256, 0, stream>>>(sbuf);
        gemm_pv<<<dim3(32, 8), 256, 0, stream>>>(sbuf, xt, (float*)d_out, b);
    }
}

// Round 4
// 893.307 us; speedup vs baseline: 2.1318x; 1.0697x over previous
//
#include <hip/hip_runtime.h>
#include <stdint.h>

typedef __attribute__((ext_vector_type(8))) short v8s;
typedef __attribute__((ext_vector_type(4))) short v4s;
typedef __attribute__((ext_vector_type(4))) float v4f;

#define MFMA(a, b, c) __builtin_amdgcn_mfma_f32_16x16x32_bf16((a), (b), (c), 0, 0, 0)

__device__ __forceinline__ unsigned short f2bf(float f) {
    unsigned int u = __float_as_uint(f);
    u += 0x7fffu + ((u >> 16) & 1u);           // RNE, inputs are finite
    return (unsigned short)(u >> 16);
}
__device__ __forceinline__ float bf2f(unsigned short h) {
    return __uint_as_float(((unsigned int)h) << 16);
}

#define NB 4
#define SEQ 4096
#define ED 1024

// ---- workspace byte offsets (peak 224 MB < proven-good 232 MB) ----
// Scratch (W splits + M^T splits, 12 MB) lives inside the tail of SBUF's
// region; it is consumed by gemm_m/gemm_y BEFORE gemm_s first writes SBUF.
#define XHI_OFF   (0ll)
#define XLO_OFF   (33554432ll)
#define XT_OFF    (67108864ll)
#define YHI_OFF   (100663296ll)
#define YLO_OFF   (134217728ll)
#define SBUF_OFF  (167772160ll)    // 64 MB: 160M..224M
#define WQH_OFF   (222298112ll)    // scratch inside SBUF tail (dead before gemm_s)
#define WQL_OFF   (224395264ll)
#define WKH_OFF   (226492416ll)
#define WKL_OFF   (228589568ll)
#define MTH_OFF   (230686720ll)
#define MTL_OFF   (232783872ll)
#define WS_NEED   (234881024ll)    // 224 MB

// ============ prep_x: split X -> bf16 hi/lo, and transpose -> XT[b][d][s] ============
__global__ __launch_bounds__(256) void prep_x(const float* __restrict__ x,
                                              unsigned short* __restrict__ xhi,
                                              unsigned short* __restrict__ xlo,
                                              unsigned short* __restrict__ xt) {
    __shared__ float tile[64][65];
    int b = blockIdx.z, s0 = blockIdx.x * 64, d0 = blockIdx.y * 64;
    int t = threadIdx.x;
#pragma unroll
    for (int i = 0; i < 16; ++i) {
        int idx = t + i * 256;
        int r = idx >> 6, c = idx & 63;
        long gi = (long)(b * SEQ + s0 + r) * ED + d0 + c;
        float v = x[gi];
        tile[r][c] = v;
        unsigned short hi = f2bf(v);
        xhi[gi] = hi;
        xlo[gi] = f2bf(v - bf2f(hi));
    }
    __syncthreads();
#pragma unroll
    for (int i = 0; i < 16; ++i) {
        int idx = t + i * 256;
        int r = idx >> 6, c = idx & 63;   // r: local d, c: local s
        xt[(long)(b * ED + d0 + r) * SEQ + s0 + c] = f2bf(tile[c][r]);
    }
}

// ============ prep_w2: split Wq, Wk (row-major, no transpose) into bf16 hi/lo ============
__global__ __launch_bounds__(256) void prep_w2(const float* __restrict__ wq,
                                               const float* __restrict__ wk,
                                               unsigned short* __restrict__ wqh,
                                               unsigned short* __restrict__ wql,
                                               unsigned short* __restrict__ wkh,
                                               unsigned short* __restrict__ wkl) {
    const float* w = blockIdx.z ? wk : wq;
    unsigned short* oh = blockIdx.z ? wkh : wqh;
    unsigned short* ol = blockIdx.z ? wkl : wql;
    long idx = ((long)blockIdx.x * 256 + threadIdx.x) * 4;
    v4f v = *(const v4f*)(w + idx);
    v4s ph, pl;
#pragma unroll
    for (int e = 0; e < 4; ++e) {
        unsigned short hi = f2bf(v[e]);
        ph[e] = (short)hi;
        pl[e] = (short)f2bf(v[e] - bf2f(hi));
    }
    *(v4s*)(oh + idx) = ph;
    *(v4s*)(ol + idx) = pl;
}

// ============ gemm_m: MT[e'][e] = sum_f Wk[e'][f] * Wq[e][f]  (4-pass split, exact-ish) ====
// A = Wk rows (hi/lo), B^T = Wq rows (hi/lo). Output = M^T row-major, split hi/lo.
__global__ __launch_bounds__(256, 2) void gemm_m(const unsigned short* __restrict__ ah,
                                                 const unsigned short* __restrict__ al,
                                                 const unsigned short* __restrict__ bh,
                                                 const unsigned short* __restrict__ bl,
                                                 unsigned short* __restrict__ ch,
                                                 unsigned short* __restrict__ cl) {
    __shared__ __align__(16) unsigned char lds[65536];
    int m0 = blockIdx.x * 128, n0 = blockIdx.y * 128;
    int tid = threadIdx.x, lane = tid & 63, wave = tid >> 6;
    int mo = (wave & 1) * 64, no = (wave >> 1) * 64;
    v4f vzero = {0.f, 0.f, 0.f, 0.f};
    v4f acc[4][4];
#pragma unroll
    for (int i = 0; i < 4; ++i)
#pragma unroll
        for (int j = 0; j < 4; ++j) acc[i][j] = vzero;
    int cb0 = 16 * (lane >> 4);

    for (int ks = 0; ks < 16; ++ks) {
        __syncthreads();
#pragma unroll
        for (int j = 0; j < 4; ++j) {
            int idx = (j * 256 + tid) * 16;
            int row = idx >> 7, cb = idx & 127;
            int sw = cb ^ ((row & 7) << 4);
            long abyte = ((long)(m0 + row) * ED + ks * 64) * 2 + cb;
            long bbyte = ((long)(n0 + row) * ED + ks * 64) * 2 + cb;
            *(v8s*)(lds +         row * 128 + sw) = *(const v8s*)((const unsigned char*)ah + abyte);
            *(v8s*)(lds + 16384 + row * 128 + sw) = *(const v8s*)((const unsigned char*)al + abyte);
            *(v8s*)(lds + 32768 + row * 128 + sw) = *(const v8s*)((const unsigned char*)bh + bbyte);
            *(v8s*)(lds + 49152 + row * 128 + sw) = *(const v8s*)((const unsigned char*)bl + bbyte);
        }
        __syncthreads();
#pragma unroll
        for (int kk = 0; kk < 2; ++kk) {
            v8s fah[4], fal[4], fbh[4], fbl[4];
#pragma unroll
            for (int i = 0; i < 4; ++i) {
                int ra = mo + i * 16 + (lane & 15);
                int ca = (kk * 64 + cb0) ^ ((ra & 7) << 4);
                fah[i] = *(const v8s*)(lds +         ra * 128 + ca);
                fal[i] = *(const v8s*)(lds + 16384 + ra * 128 + ca);
                int rb = no + i * 16 + (lane & 15);
                int cbb = (kk * 64 + cb0) ^ ((rb & 7) << 4);
                fbh[i] = *(const v8s*)(lds + 32768 + rb * 128 + cbb);
                fbl[i] = *(const v8s*)(lds + 49152 + rb * 128 + cbb);
            }
#pragma unroll
            for (int i = 0; i < 4; ++i)
#pragma unroll
                for (int j = 0; j < 4; ++j) {
                    acc[i][j] = MFMA(fah[i], fbh[j], acc[i][j]);
                    acc[i][j] = MFMA(fah[i], fbl[j], acc[i][j]);
                    acc[i][j] = MFMA(fal[i], fbh[j], acc[i][j]);
                    acc[i][j] = MFMA(fal[i], fbl[j], acc[i][j]);   // 4th pass: full product
                }
        }
    }
#pragma unroll
    for (int i = 0; i < 4; ++i)
#pragma unroll
        for (int j = 0; j < 4; ++j)
#pragma unroll
            for (int r = 0; r < 4; ++r) {
                int row = m0 + mo + i * 16 + (lane >> 4) * 4 + r;
                int col = n0 + no + j * 16 + (lane & 15);
                float v = acc[i][j][r];
                unsigned short hi = f2bf(v);
                long o = (long)row * ED + col;
                ch[o] = hi;
                cl[o] = f2bf(v - bf2f(hi));
            }
}

// ============ gemm_y: Y[16384,1024] = X x M  (A=x hi/lo, B^T=M^T hi/lo, 3 passes) ============
__global__ __launch_bounds__(256, 2) void gemm_y(const unsigned short* __restrict__ ah,
                                                 const unsigned short* __restrict__ al,
                                                 const unsigned short* __restrict__ bh,
                                                 const unsigned short* __restrict__ bl,
                                                 unsigned short* __restrict__ ch,
                                                 unsigned short* __restrict__ cl) {
    __shared__ __align__(16) unsigned char lds[65536];
    int m0 = blockIdx.x * 128, n0 = blockIdx.y * 128;
    int tid = threadIdx.x, lane = tid & 63, wave = tid >> 6;
    int mo = (wave & 1) * 64, no = (wave >> 1) * 64;
    v4f vzero = {0.f, 0.f, 0.f, 0.f};
    v4f acc[4][4];
#pragma unroll
    for (int i = 0; i < 4; ++i)
#pragma unroll
        for (int j = 0; j < 4; ++j) acc[i][j] = vzero;
    int cb0 = 16 * (lane >> 4);

    for (int ks = 0; ks < 16; ++ks) {
        __syncthreads();
#pragma unroll
        for (int j = 0; j < 4; ++j) {
            int idx = (j * 256 + tid) * 16;
            int row = idx >> 7, cb = idx & 127;
            int sw = cb ^ ((row & 7) << 4);
            long abyte = ((long)(m0 + row) * ED + ks * 64) * 2 + cb;
            long bbyte = ((long)(n0 + row) * ED + ks * 64) * 2 + cb;
            *(v8s*)(lds +         row * 128 + sw) = *(const v8s*)((const unsigned char*)ah + abyte);
            *(v8s*)(lds + 16384 + row * 128 + sw) = *(const v8s*)((const unsigned char*)al + abyte);
            *(v8s*)(lds + 32768 + row * 128 + sw) = *(const v8s*)((const unsigned char*)bh + bbyte);
            *(v8s*)(lds + 49152 + row * 128 + sw) = *(const v8s*)((const unsigned char*)bl + bbyte);
        }
        __syncthreads();
#pragma unroll
        for (int kk = 0; kk < 2; ++kk) {
            v8s fah[4], fal[4], fbh[4], fbl[4];
#pragma unroll
            for (int i = 0; i < 4; ++i) {
                int ra = mo + i * 16 + (lane & 15);
                int ca = (kk * 64 + cb0) ^ ((ra & 7) << 4);
                fah[i] = *(const v8s*)(lds +         ra * 128 + ca);
                fal[i] = *(const v8s*)(lds + 16384 + ra * 128 + ca);
                int rb = no + i * 16 + (lane & 15);
                int cbb = (kk * 64 + cb0) ^ ((rb & 7) << 4);
                fbh[i] = *(const v8s*)(lds + 32768 + rb * 128 + cbb);
                fbl[i] = *(const v8s*)(lds + 49152 + rb * 128 + cbb);
            }
#pragma unroll
            for (int i = 0; i < 4; ++i)
#pragma unroll
                for (int j = 0; j < 4; ++j) {
                    acc[i][j] = MFMA(fah[i], fbh[j], acc[i][j]);
                    acc[i][j] = MFMA(fah[i], fbl[j], acc[i][j]);
                    acc[i][j] = MFMA(fal[i], fbh[j], acc[i][j]);
                }
        }
    }
#pragma unroll
    for (int i = 0; i < 4; ++i)
#pragma unroll
        for (int j = 0; j < 4; ++j)
#pragma unroll
            for (int r = 0; r < 4; ++r) {
                int row = m0 + mo + i * 16 + (lane >> 4) * 4 + r;
                int col = n0 + no + j * 16 + (lane & 15);
                float v = acc[i][j][r];
                unsigned short hi = f2bf(v);
                long o = (long)row * ED + col;
                ch[o] = hi;
                cl[o] = f2bf(v - bf2f(hi));
            }
}

// ============ gemm_s: S[q][t] = (Y X^T)/32 for one batch, fp32 into sbuf ============
__global__ __launch_bounds__(256, 2) void gemm_s(const unsigned short* __restrict__ qhi,
                                                 const unsigned short* __restrict__ qlo,
                                                 const unsigned short* __restrict__ khi,
                                                 const unsigned short* __restrict__ klo,
                                                 float* __restrict__ sbuf, int b) {
    __shared__ __align__(16) unsigned char lds[65536];
    int m0 = blockIdx.x * 128, n0 = blockIdx.y * 128;
    int tid = threadIdx.x, lane = tid & 63, wave = tid >> 6;
    int mo = (wave & 1) * 64, no = (wave >> 1) * 64;
    v4f vzero = {0.f, 0.f, 0.f, 0.f};
    v4f acc[4][4];
#pragma unroll
    for (int i = 0; i < 4; ++i)
#pragma unroll
        for (int j = 0; j < 4; ++j) acc[i][j] = vzero;
    int cb0 = 16 * (lane >> 4);

    for (int ks = 0; ks < 16; ++ks) {
        __syncthreads();
#pragma unroll
        for (int j = 0; j < 4; ++j) {
            int idx = (j * 256 + tid) * 16;
            int row = idx >> 7, cb = idx & 127;
            int sw = cb ^ ((row & 7) << 4);
            long abyte = ((long)(b * SEQ + m0 + row) * ED + ks * 64) * 2 + cb;
            long bbyte = ((long)(b * SEQ + n0 + row) * ED + ks * 64) * 2 + cb;
            *(v8s*)(lds +         row * 128 + sw) = *(const v8s*)((const unsigned char*)qhi + abyte);
            *(v8s*)(lds + 16384 + row * 128 + sw) = *(const v8s*)((const unsigned char*)qlo + abyte);
            *(v8s*)(lds + 32768 + row * 128 + sw) = *(const v8s*)((const unsigned char*)khi + bbyte);
            *(v8s*)(lds + 49152 + row * 128 + sw) = *(const v8s*)((const unsigned char*)klo + bbyte);
        }
        __syncthreads();
#pragma unroll
        for (int kk = 0; kk < 2; ++kk) {
            v8s fah[4], fal[4], fbh[4], fbl[4];
#pragma unroll
            for (int i = 0; i < 4; ++i) {
                int ra = mo + i * 16 + (lane & 15);
                int ca = (kk * 64 + cb0) ^ ((ra & 7) << 4);
                fah[i] = *(const v8s*)(lds +         ra * 128 + ca);
                fal[i] = *(const v8s*)(lds + 16384 + ra * 128 + ca);
                int rb = no + i * 16 + (lane & 15);
                int cbb = (kk * 64 + cb0) ^ ((rb & 7) << 4);
                fbh[i] = *(const v8s*)(lds + 32768 + rb * 128 + cbb);
                fbl[i] = *(const v8s*)(lds + 49152 + rb * 128 + cbb);
            }
#pragma unroll
            for (int i = 0; i < 4; ++i)
#pragma unroll
                for (int j = 0; j < 4; ++j) {
                    acc[i][j] = MFMA(fah[i], fbh[j], acc[i][j]);
                    acc[i][j] = MFMA(fah[i], fbl[j], acc[i][j]);
                    acc[i][j] = MFMA(fal[i], fbh[j], acc[i][j]);
                }
        }
    }
#pragma unroll
    for (int i = 0; i < 4; ++i)
#pragma unroll
        for (int j = 0; j < 4; ++j)
#pragma unroll
            for (int r = 0; r < 4; ++r) {
                int row = m0 + mo + i * 16 + (lane >> 4) * 4 + r;
                int col = n0 + no + j * 16 + (lane & 15);
                sbuf[(long)row * SEQ + col] = acc[i][j][r] * 0.03125f;
            }
}

// ============ softmax_rows: P = exp(S-m)/l, bf16, packed in-place (first 8KB of row) ============
__global__ __launch_bounds__(256) void softmax_rows(float* __restrict__ sbuf) {
    int row = blockIdx.x * 4 + (threadIdx.x >> 6);
    int lane = threadIdx.x & 63;
    float* base = sbuf + (long)row * SEQ;
    v4f v[16];
    float m = -INFINITY;
#pragma unroll
    for (int j = 0; j < 16; ++j) {
        v[j] = *(const v4f*)(base + j * 256 + lane * 4);
#pragma unroll
        for (int e = 0; e < 4; ++e) m = fmaxf(m, v[j][e]);
    }
#pragma unroll
    for (int o = 1; o < 64; o <<= 1) m = fmaxf(m, __shfl_xor(m, o));
    float s = 0.f;
#pragma unroll
    for (int j = 0; j < 16; ++j)
#pragma unroll
        for (int e = 0; e < 4; ++e) {
            float p = __expf(v[j][e] - m);
            s += p;
            v[j][e] = p;
        }
#pragma unroll
    for (int o = 1; o < 64; o <<= 1) s += __shfl_xor(s, o);
    float inv = 1.0f / s;
    unsigned short* ob = (unsigned short*)base;
#pragma unroll
    for (int j = 0; j < 16; ++j) {
        v4s pk;
#pragma unroll
        for (int e = 0; e < 4; ++e) pk[e] = (short)f2bf(v[j][e] * inv);
        *(v4s*)(ob + j * 256 + lane * 4) = pk;
    }
}

// ============ gemm_pv: O[q][d] = P X for one batch. A = P (16KB row slots), B^T = XT ============
__global__ __launch_bounds__(256, 4) void gemm_pv(const float* __restrict__ sbuf,
                                                  const unsigned short* __restrict__ xt,
                                                  float* __restrict__ out, int b) {
    __shared__ __align__(16) unsigned char lds[32768];
    int m0 = blockIdx.x * 128, n0 = blockIdx.y * 128;
    int tid = threadIdx.x, lane = tid & 63, wave = tid >> 6;
    int mo = (wave & 1) * 64, no = (wave >> 1) * 64;
    const unsigned char* pbytes = (const unsigned char*)sbuf;
    v4f vzero = {0.f, 0.f, 0.f, 0.f};
    v4f acc[4][4];
#pragma unroll
    for (int i = 0; i < 4; ++i)
#pragma unroll
        for (int j = 0; j < 4; ++j) acc[i][j] = vzero;
    int cb0 = 16 * (lane >> 4);

    for (int ks = 0; ks < 64; ++ks) {
        __syncthreads();
#pragma unroll
        for (int j = 0; j < 4; ++j) {
            int idx = (j * 256 + tid) * 16;
            int row = idx >> 7, cb = idx & 127;
            int sw = cb ^ ((row & 7) << 4);
            long abyte = (long)(m0 + row) * 16384 + ks * 128 + cb;
            long bbyte = ((long)(b * ED + n0 + row) * SEQ + ks * 64) * 2 + cb;
            *(v8s*)(lds +         row * 128 + sw) = *(const v8s*)(pbytes + abyte);
            *(v8s*)(lds + 16384 + row * 128 + sw) = *(const v8s*)((const unsigned char*)xt + bbyte);
        }
        __syncthreads();
#pragma unroll
        for (int kk = 0; kk < 2; ++kk) {
            v8s fa[4], fb[4];
#pragma unroll
            for (int i = 0; i < 4; ++i) {
                int ra = mo + i * 16 + (lane & 15);
                int ca = (kk * 64 + cb0) ^ ((ra & 7) << 4);
                fa[i] = *(const v8s*)(lds +         ra * 128 + ca);
                int rb = no + i * 16 + (lane & 15);
                int cbb = (kk * 64 + cb0) ^ ((rb & 7) << 4);
                fb[i] = *(const v8s*)(lds + 16384 + rb * 128 + cbb);
            }
#pragma unroll
            for (int i = 0; i < 4; ++i)
#pragma unroll
                for (int j = 0; j < 4; ++j)
                    acc[i][j] = MFMA(fa[i], fb[j], acc[i][j]);
        }
    }
#pragma unroll
    for (int i = 0; i < 4; ++i)
#pragma unroll
        for (int j = 0; j < 4; ++j)
#pragma unroll
            for (int r = 0; r < 4; ++r) {
                int row = m0 + mo + i * 16 + (lane >> 4) * 4 + r;
                int col = n0 + no + j * 16 + (lane & 15);
                out[(long)(b * SEQ + row) * ED + col] = acc[i][j][r];
            }
}

extern "C" void kernel_launch(void* const* d_in, const int* in_sizes, int n_in,
                              void* d_out, int out_size, void* d_ws, size_t ws_size,
                              hipStream_t stream) {
    const float* x  = (const float*)d_in[0];
    const float* wq = (const float*)d_in[1];
    const float* wk = (const float*)d_in[2];
    unsigned char* ws = (unsigned char*)d_ws;
    unsigned short* xhi = (unsigned short*)(ws + XHI_OFF);
    unsigned short* xlo = (unsigned short*)(ws + XLO_OFF);
    unsigned short* xt  = (unsigned short*)(ws + XT_OFF);
    unsigned short* yhi = (unsigned short*)(ws + YHI_OFF);
    unsigned short* ylo = (unsigned short*)(ws + YLO_OFF);
    float*          sbuf= (float*)(ws + SBUF_OFF);
    unsigned short* wqh = (unsigned short*)(ws + WQH_OFF);
    unsigned short* wql = (unsigned short*)(ws + WQL_OFF);
    unsigned short* wkh = (unsigned short*)(ws + WKH_OFF);
    unsigned short* wkl = (unsigned short*)(ws + WKL_OFF);
    unsigned short* mth = (unsigned short*)(ws + MTH_OFF);
    unsigned short* mtl = (unsigned short*)(ws + MTL_OFF);

    prep_x<<<dim3(64, 16, 4), 256, 0, stream>>>(x, xhi, xlo, xt);
    prep_w2<<<dim3(1024, 1, 2), 256, 0, stream>>>(wq, wk, wqh, wql, wkh, wkl);
    // MT = Wk * Wq^T  (i.e. M^T, row-major), split hi/lo
    gemm_m<<<dim3(8, 8), 256, 0, stream>>>(wkh, wkl, wqh, wql, mth, mtl);
    // Y = X * M  (B^T = M^T rows), split hi/lo
    gemm_y<<<dim3(128, 8), 256, 0, stream>>>(xhi, xlo, mth, mtl, yhi, ylo);
    for (int b = 0; b < NB; ++b) {
        gemm_s<<<dim3(32, 32), 256, 0, stream>>>(yhi, ylo, xhi, xlo, sbuf, b);
        softmax_rows<<<1024, 256, 0, stream>>>(sbuf);
        gemm_pv<<<dim3(32, 8), 256, 0, stream>>>(sbuf, xt, (float*)d_out, b);
    }
}

// Round 5
// 827.732 us; speedup vs baseline: 2.3007x; 1.0792x over previous
//
#include <hip/hip_runtime.h>
#include <stdint.h>

typedef __attribute__((ext_vector_type(8))) short v8s;
typedef __attribute__((ext_vector_type(4))) short v4s;
typedef __attribute__((ext_vector_type(4))) float v4f;

#define MFMA(a, b, c) __builtin_amdgcn_mfma_f32_16x16x32_bf16((a), (b), (c), 0, 0, 0)

__device__ __forceinline__ unsigned short f2bf(float f) {
    unsigned int u = __float_as_uint(f);
    u += 0x7fffu + ((u >> 16) & 1u);           // RNE, inputs are finite
    return (unsigned short)(u >> 16);
}
__device__ __forceinline__ float bf2f(unsigned short h) {
    return __uint_as_float(((unsigned int)h) << 16);
}

// async global->LDS, 16B per lane. LDS dest = wave-uniform chunk base (+ lane*16 by HW).
__device__ __forceinline__ void gload16(const void* g, void* l) {
    __builtin_amdgcn_global_load_lds((const __attribute__((address_space(1))) void*)g,
                                     (__attribute__((address_space(3))) void*)l, 16, 0, 0);
}

#define NB 4
#define SEQ 4096
#define ED 1024

// ---- workspace byte offsets (peak 224 MB < proven-good 232 MB) ----
#define XHI_OFF   (0ll)
#define XLO_OFF   (33554432ll)
#define XT_OFF    (67108864ll)
#define YHI_OFF   (100663296ll)
#define YLO_OFF   (134217728ll)
#define SBUF_OFF  (167772160ll)    // 64 MB: 160M..224M
#define WQH_OFF   (222298112ll)    // scratch inside SBUF tail (dead before gemm_s)
#define WQL_OFF   (224395264ll)
#define WKH_OFF   (226492416ll)
#define WKL_OFF   (228589568ll)
#define MTH_OFF   (230686720ll)
#define MTL_OFF   (232783872ll)
#define WS_NEED   (234881024ll)    // 224 MB

// ============ prep_x: split X -> bf16 hi/lo, and transpose -> XT[b][d][s] ============
__global__ __launch_bounds__(256) void prep_x(const float* __restrict__ x,
                                              unsigned short* __restrict__ xhi,
                                              unsigned short* __restrict__ xlo,
                                              unsigned short* __restrict__ xt) {
    __shared__ float tile[64][65];
    int b = blockIdx.z, s0 = blockIdx.x * 64, d0 = blockIdx.y * 64;
    int t = threadIdx.x;
#pragma unroll
    for (int i = 0; i < 16; ++i) {
        int idx = t + i * 256;
        int r = idx >> 6, c = idx & 63;
        long gi = (long)(b * SEQ + s0 + r) * ED + d0 + c;
        float v = x[gi];
        tile[r][c] = v;
        unsigned short hi = f2bf(v);
        xhi[gi] = hi;
        xlo[gi] = f2bf(v - bf2f(hi));
    }
    __syncthreads();
#pragma unroll
    for (int i = 0; i < 16; ++i) {
        int idx = t + i * 256;
        int r = idx >> 6, c = idx & 63;   // r: local d, c: local s
        xt[(long)(b * ED + d0 + r) * SEQ + s0 + c] = f2bf(tile[c][r]);
    }
}

// ============ prep_w2: split Wq, Wk (row-major, no transpose) into bf16 hi/lo ============
__global__ __launch_bounds__(256) void prep_w2(const float* __restrict__ wq,
                                               const float* __restrict__ wk,
                                               unsigned short* __restrict__ wqh,
                                               unsigned short* __restrict__ wql,
                                               unsigned short* __restrict__ wkh,
                                               unsigned short* __restrict__ wkl) {
    const float* w = blockIdx.z ? wk : wq;
    unsigned short* oh = blockIdx.z ? wkh : wqh;
    unsigned short* ol = blockIdx.z ? wkl : wql;
    long idx = ((long)blockIdx.x * 256 + threadIdx.x) * 4;
    v4f v = *(const v4f*)(w + idx);
    v4s ph, pl;
#pragma unroll
    for (int e = 0; e < 4; ++e) {
        unsigned short hi = f2bf(v[e]);
        ph[e] = (short)hi;
        pl[e] = (short)f2bf(v[e] - bf2f(hi));
    }
    *(v4s*)(oh + idx) = ph;
    *(v4s*)(ol + idx) = pl;
}

// ============ gemm_m: MT[e'][e] = sum_f Wk[e'][f] * Wq[e][f]  (4-pass split) ============
__global__ __launch_bounds__(256, 2) void gemm_m(const unsigned short* __restrict__ ah,
                                                 const unsigned short* __restrict__ al,
                                                 const unsigned short* __restrict__ bh,
                                                 const unsigned short* __restrict__ bl,
                                                 unsigned short* __restrict__ ch,
                                                 unsigned short* __restrict__ cl) {
    __shared__ __align__(16) unsigned char lds[65536];
    int m0 = blockIdx.x * 128, n0 = blockIdx.y * 128;
    int tid = threadIdx.x, lane = tid & 63, wave = tid >> 6;
    int mo = (wave & 1) * 64, no = (wave >> 1) * 64;
    int lr = lane >> 3;                              // row within 8-row chunk
    int scol = (((lane & 7) ^ lr) << 4);             // pre-swizzled source col (bytes)
    v4f vzero = {0.f, 0.f, 0.f, 0.f};
    v4f acc[4][4];
#pragma unroll
    for (int i = 0; i < 4; ++i)
#pragma unroll
        for (int j = 0; j < 4; ++j) acc[i][j] = vzero;
    int cb0 = 16 * (lane >> 4);

    for (int ks = 0; ks < 16; ++ks) {
        __syncthreads();   // protect prior reads before DMA overwrite
#pragma unroll
        for (int j = 0; j < 4; ++j) {
            int c = j * 4 + wave;                    // 1KB chunk 0..15
            int row = c * 8 + lr;                    // tile row 0..127
            long ga = ((long)(m0 + row) * ED + ks * 64) * 2 + scol;
            long gb = ((long)(n0 + row) * ED + ks * 64) * 2 + scol;
            unsigned loff = c * 1024;
            gload16((const unsigned char*)ah + ga, lds + loff);
            gload16((const unsigned char*)al + ga, lds + 16384 + loff);
            gload16((const unsigned char*)bh + gb, lds + 32768 + loff);
            gload16((const unsigned char*)bl + gb, lds + 49152 + loff);
        }
        __syncthreads();
#pragma unroll
        for (int kk = 0; kk < 2; ++kk) {
            v8s fah[4], fal[4], fbh[4], fbl[4];
#pragma unroll
            for (int i = 0; i < 4; ++i) {
                int ra = mo + i * 16 + (lane & 15);
                int ca = (kk * 64 + cb0) ^ ((ra & 7) << 4);
                fah[i] = *(const v8s*)(lds +         ra * 128 + ca);
                fal[i] = *(const v8s*)(lds + 16384 + ra * 128 + ca);
                int rb = no + i * 16 + (lane & 15);
                int cbb = (kk * 64 + cb0) ^ ((rb & 7) << 4);
                fbh[i] = *(const v8s*)(lds + 32768 + rb * 128 + cbb);
                fbl[i] = *(const v8s*)(lds + 49152 + rb * 128 + cbb);
            }
#pragma unroll
            for (int i = 0; i < 4; ++i)
#pragma unroll
                for (int j = 0; j < 4; ++j) {
                    acc[i][j] = MFMA(fah[i], fbh[j], acc[i][j]);
                    acc[i][j] = MFMA(fah[i], fbl[j], acc[i][j]);
                    acc[i][j] = MFMA(fal[i], fbh[j], acc[i][j]);
                    acc[i][j] = MFMA(fal[i], fbl[j], acc[i][j]);
                }
        }
    }
#pragma unroll
    for (int i = 0; i < 4; ++i)
#pragma unroll
        for (int j = 0; j < 4; ++j)
#pragma unroll
            for (int r = 0; r < 4; ++r) {
                int row = m0 + mo + i * 16 + (lane >> 4) * 4 + r;
                int col = n0 + no + j * 16 + (lane & 15);
                float v = acc[i][j][r];
                unsigned short hi = f2bf(v);
                long o = (long)row * ED + col;
                ch[o] = hi;
                cl[o] = f2bf(v - bf2f(hi));
            }
}

// ============ gemm_y: Y[16384,1024] = X x M  (A=x hi/lo, B^T=M^T hi/lo, 3 passes) ============
__global__ __launch_bounds__(256, 2) void gemm_y(const unsigned short* __restrict__ ah,
                                                 const unsigned short* __restrict__ al,
                                                 const unsigned short* __restrict__ bh,
                                                 const unsigned short* __restrict__ bl,
                                                 unsigned short* __restrict__ ch,
                                                 unsigned short* __restrict__ cl) {
    __shared__ __align__(16) unsigned char lds[65536];
    int m0 = blockIdx.x * 128, n0 = blockIdx.y * 128;
    int tid = threadIdx.x, lane = tid & 63, wave = tid >> 6;
    int mo = (wave & 1) * 64, no = (wave >> 1) * 64;
    int lr = lane >> 3;
    int scol = (((lane & 7) ^ lr) << 4);
    v4f vzero = {0.f, 0.f, 0.f, 0.f};
    v4f acc[4][4];
#pragma unroll
    for (int i = 0; i < 4; ++i)
#pragma unroll
        for (int j = 0; j < 4; ++j) acc[i][j] = vzero;
    int cb0 = 16 * (lane >> 4);

    for (int ks = 0; ks < 16; ++ks) {
        __syncthreads();
#pragma unroll
        for (int j = 0; j < 4; ++j) {
            int c = j * 4 + wave;
            int row = c * 8 + lr;
            long ga = ((long)(m0 + row) * ED + ks * 64) * 2 + scol;
            long gb = ((long)(n0 + row) * ED + ks * 64) * 2 + scol;
            unsigned loff = c * 1024;
            gload16((const unsigned char*)ah + ga, lds + loff);
            gload16((const unsigned char*)al + ga, lds + 16384 + loff);
            gload16((const unsigned char*)bh + gb, lds + 32768 + loff);
            gload16((const unsigned char*)bl + gb, lds + 49152 + loff);
        }
        __syncthreads();
#pragma unroll
        for (int kk = 0; kk < 2; ++kk) {
            v8s fah[4], fal[4], fbh[4], fbl[4];
#pragma unroll
            for (int i = 0; i < 4; ++i) {
                int ra = mo + i * 16 + (lane & 15);
                int ca = (kk * 64 + cb0) ^ ((ra & 7) << 4);
                fah[i] = *(const v8s*)(lds +         ra * 128 + ca);
                fal[i] = *(const v8s*)(lds + 16384 + ra * 128 + ca);
                int rb = no + i * 16 + (lane & 15);
                int cbb = (kk * 64 + cb0) ^ ((rb & 7) << 4);
                fbh[i] = *(const v8s*)(lds + 32768 + rb * 128 + cbb);
                fbl[i] = *(const v8s*)(lds + 49152 + rb * 128 + cbb);
            }
#pragma unroll
            for (int i = 0; i < 4; ++i)
#pragma unroll
                for (int j = 0; j < 4; ++j) {
                    acc[i][j] = MFMA(fah[i], fbh[j], acc[i][j]);
                    acc[i][j] = MFMA(fah[i], fbl[j], acc[i][j]);
                    acc[i][j] = MFMA(fal[i], fbh[j], acc[i][j]);
                }
        }
    }
#pragma unroll
    for (int i = 0; i < 4; ++i)
#pragma unroll
        for (int j = 0; j < 4; ++j)
#pragma unroll
            for (int r = 0; r < 4; ++r) {
                int row = m0 + mo + i * 16 + (lane >> 4) * 4 + r;
                int col = n0 + no + j * 16 + (lane & 15);
                float v = acc[i][j][r];
                unsigned short hi = f2bf(v);
                long o = (long)row * ED + col;
                ch[o] = hi;
                cl[o] = f2bf(v - bf2f(hi));
            }
}

// ============ gemm_s: S[q][t] = (Y X^T)/32 for one batch, fp32 into sbuf ============
__global__ __launch_bounds__(256, 2) void gemm_s(const unsigned short* __restrict__ qhi,
                                                 const unsigned short* __restrict__ qlo,
                                                 const unsigned short* __restrict__ khi,
                                                 const unsigned short* __restrict__ klo,
                                                 float* __restrict__ sbuf, int b) {
    __shared__ __align__(16) unsigned char lds[65536];
    int m0 = blockIdx.x * 128, n0 = blockIdx.y * 128;
    int tid = threadIdx.x, lane = tid & 63, wave = tid >> 6;
    int mo = (wave & 1) * 64, no = (wave >> 1) * 64;
    int lr = lane >> 3;
    int scol = (((lane & 7) ^ lr) << 4);
    v4f vzero = {0.f, 0.f, 0.f, 0.f};
    v4f acc[4][4];
#pragma unroll
    for (int i = 0; i < 4; ++i)
#pragma unroll
        for (int j = 0; j < 4; ++j) acc[i][j] = vzero;
    int cb0 = 16 * (lane >> 4);

    for (int ks = 0; ks < 16; ++ks) {
        __syncthreads();
#pragma unroll
        for (int j = 0; j < 4; ++j) {
            int c = j * 4 + wave;
            int row = c * 8 + lr;
            long ga = ((long)(b * SEQ + m0 + row) * ED + ks * 64) * 2 + scol;
            long gb = ((long)(b * SEQ + n0 + row) * ED + ks * 64) * 2 + scol;
            unsigned loff = c * 1024;
            gload16((const unsigned char*)qhi + ga, lds + loff);
            gload16((const unsigned char*)qlo + ga, lds + 16384 + loff);
            gload16((const unsigned char*)khi + gb, lds + 32768 + loff);
            gload16((const unsigned char*)klo + gb, lds + 49152 + loff);
        }
        __syncthreads();
#pragma unroll
        for (int kk = 0; kk < 2; ++kk) {
            v8s fah[4], fal[4], fbh[4], fbl[4];
#pragma unroll
            for (int i = 0; i < 4; ++i) {
                int ra = mo + i * 16 + (lane & 15);
                int ca = (kk * 64 + cb0) ^ ((ra & 7) << 4);
                fah[i] = *(const v8s*)(lds +         ra * 128 + ca);
                fal[i] = *(const v8s*)(lds + 16384 + ra * 128 + ca);
                int rb = no + i * 16 + (lane & 15);
                int cbb = (kk * 64 + cb0) ^ ((rb & 7) << 4);
                fbh[i] = *(const v8s*)(lds + 32768 + rb * 128 + cbb);
                fbl[i] = *(const v8s*)(lds + 49152 + rb * 128 + cbb);
            }
#pragma unroll
            for (int i = 0; i < 4; ++i)
#pragma unroll
                for (int j = 0; j < 4; ++j) {
                    acc[i][j] = MFMA(fah[i], fbh[j], acc[i][j]);
                    acc[i][j] = MFMA(fah[i], fbl[j], acc[i][j]);
                    acc[i][j] = MFMA(fal[i], fbh[j], acc[i][j]);
                }
        }
    }
#pragma unroll
    for (int i = 0; i < 4; ++i)
#pragma unroll
        for (int j = 0; j < 4; ++j)
#pragma unroll
            for (int r = 0; r < 4; ++r) {
                int row = m0 + mo + i * 16 + (lane >> 4) * 4 + r;
                int col = n0 + no + j * 16 + (lane & 15);
                sbuf[(long)row * SEQ + col] = acc[i][j][r] * 0.03125f;
            }
}

// ============ softmax_rows: P = exp(S-m)/l, bf16, packed in-place (first 8KB of row) ============
__global__ __launch_bounds__(256) void softmax_rows(float* __restrict__ sbuf) {
    int row = blockIdx.x * 4 + (threadIdx.x >> 6);
    int lane = threadIdx.x & 63;
    float* base = sbuf + (long)row * SEQ;
    v4f v[16];
    float m = -INFINITY;
#pragma unroll
    for (int j = 0; j < 16; ++j) {
        v[j] = *(const v4f*)(base + j * 256 + lane * 4);
#pragma unroll
        for (int e = 0; e < 4; ++e) m = fmaxf(m, v[j][e]);
    }
#pragma unroll
    for (int o = 1; o < 64; o <<= 1) m = fmaxf(m, __shfl_xor(m, o));
    float s = 0.f;
#pragma unroll
    for (int j = 0; j < 16; ++j)
#pragma unroll
        for (int e = 0; e < 4; ++e) {
            float p = __expf(v[j][e] - m);
            s += p;
            v[j][e] = p;
        }
#pragma unroll
    for (int o = 1; o < 64; o <<= 1) s += __shfl_xor(s, o);
    float inv = 1.0f / s;
    unsigned short* ob = (unsigned short*)base;
#pragma unroll
    for (int j = 0; j < 16; ++j) {
        v4s pk;
#pragma unroll
        for (int e = 0; e < 4; ++e) pk[e] = (short)f2bf(v[j][e] * inv);
        *(v4s*)(ob + j * 256 + lane * 4) = pk;
    }
}

// ============ gemm_pv: O[q][d] = P X for one batch. A = P (16KB row slots), B^T = XT ============
__global__ __launch_bounds__(256, 4) void gemm_pv(const float* __restrict__ sbuf,
                                                  const unsigned short* __restrict__ xt,
                                                  float* __restrict__ out, int b) {
    __shared__ __align__(16) unsigned char lds[32768];
    int m0 = blockIdx.x * 128, n0 = blockIdx.y * 128;
    int tid = threadIdx.x, lane = tid & 63, wave = tid >> 6;
    int mo = (wave & 1) * 64, no = (wave >> 1) * 64;
    const unsigned char* pbytes = (const unsigned char*)sbuf;
    int lr = lane >> 3;
    int scol = (((lane & 7) ^ lr) << 4);
    v4f vzero = {0.f, 0.f, 0.f, 0.f};
    v4f acc[4][4];
#pragma unroll
    for (int i = 0; i < 4; ++i)
#pragma unroll
        for (int j = 0; j < 4; ++j) acc[i][j] = vzero;
    int cb0 = 16 * (lane >> 4);

    for (int ks = 0; ks < 64; ++ks) {
        __syncthreads();
#pragma unroll
        for (int j = 0; j < 4; ++j) {
            int c = j * 4 + wave;
            int row = c * 8 + lr;
            long ga = (long)(m0 + row) * 16384 + ks * 128 + scol;        // P row slot stride 16KB
            long gb = ((long)(b * ED + n0 + row) * SEQ + ks * 64) * 2 + scol;
            unsigned loff = c * 1024;
            gload16(pbytes + ga, lds + loff);
            gload16((const unsigned char*)xt + gb, lds + 16384 + loff);
        }
        __syncthreads();
#pragma unroll
        for (int kk = 0; kk < 2; ++kk) {
            v8s fa[4], fb[4];
#pragma unroll
            for (int i = 0; i < 4; ++i) {
                int ra = mo + i * 16 + (lane & 15);
                int ca = (kk * 64 + cb0) ^ ((ra & 7) << 4);
                fa[i] = *(const v8s*)(lds +         ra * 128 + ca);
                int rb = no + i * 16 + (lane & 15);
                int cbb = (kk * 64 + cb0) ^ ((rb & 7) << 4);
                fb[i] = *(const v8s*)(lds + 16384 + rb * 128 + cbb);
            }
#pragma unroll
            for (int i = 0; i < 4; ++i)
#pragma unroll
                for (int j = 0; j < 4; ++j)
                    acc[i][j] = MFMA(fa[i], fb[j], acc[i][j]);
        }
    }
#pragma unroll
    for (int i = 0; i < 4; ++i)
#pragma unroll
        for (int j = 0; j < 4; ++j)
#pragma unroll
            for (int r = 0; r < 4; ++r) {
                int row = m0 + mo + i * 16 + (lane >> 4) * 4 + r;
                int col = n0 + no + j * 16 + (lane & 15);
                out[(long)(b * SEQ + row) * ED + col] = acc[i][j][r];
            }
}

extern "C" void kernel_launch(void* const* d_in, const int* in_sizes, int n_in,
                              void* d_out, int out_size, void* d_ws, size_t ws_size,
                              hipStream_t stream) {
    const float* x  = (const float*)d_in[0];
    const float* wq = (const float*)d_in[1];
    const float* wk = (const float*)d_in[2];
    unsigned char* ws = (unsigned char*)d_ws;
    unsigned short* xhi = (unsigned short*)(ws + XHI_OFF);
    unsigned short* xlo = (unsigned short*)(ws + XLO_OFF);
    unsigned short* xt  = (unsigned short*)(ws + XT_OFF);
    unsigned short* yhi = (unsigned short*)(ws + YHI_OFF);
    unsigned short* ylo = (unsigned short*)(ws + YLO_OFF);
    float*          sbuf= (float*)(ws + SBUF_OFF);
    unsigned short* wqh = (unsigned short*)(ws + WQH_OFF);
    unsigned short* wql = (unsigned short*)(ws + WQL_OFF);
    unsigned short* wkh = (unsigned short*)(ws + WKH_OFF);
    unsigned short* wkl = (unsigned short*)(ws + WKL_OFF);
    unsigned short* mth = (unsigned short*)(ws + MTH_OFF);
    unsigned short* mtl = (unsigned short*)(ws + MTL_OFF);

    prep_x<<<dim3(64, 16, 4), 256, 0, stream>>>(x, xhi, xlo, xt);
    prep_w2<<<dim3(1024, 1, 2), 256, 0, stream>>>(wq, wk, wqh, wql, wkh, wkl);
    gemm_m<<<dim3(8, 8), 256, 0, stream>>>(wkh, wkl, wqh, wql, mth, mtl);
    gemm_y<<<dim3(128, 8), 256, 0, stream>>>(xhi, xlo, mth, mtl, yhi, ylo);
    for (int b = 0; b < NB; ++b) {
        gemm_s<<<dim3(32, 32), 256, 0, stream>>>(yhi, ylo, xhi, xlo, sbuf, b);
        softmax_rows<<<1024, 256, 0, stream>>>(sbuf);
        gemm_pv<<<dim3(32, 8), 256, 0, stream>>>(sbuf, xt, (float*)d_out, b);
    }
}